// Round 4
// baseline (402.232 us; speedup 1.0000x reference)
//
#include <hip/hip_runtime.h>
#include <stdint.h>

#define NB 32
#define NL 1024
#define ND 256

typedef __attribute__((ext_vector_type(8))) __bf16 bf16x8;
typedef __attribute__((ext_vector_type(4))) uint16_t u16x4;
typedef __attribute__((ext_vector_type(4))) float f32x4;

__device__ __forceinline__ uint16_t f2bf(float f) {
  union { float f; uint32_t u; } v; v.f = f;
  return (uint16_t)((v.u + 0x7fffu + ((v.u >> 16) & 1u)) >> 16);
}
__device__ __forceinline__ float bf2f(uint16_t h) {
  union { uint32_t u; float f; } v; v.u = ((uint32_t)h) << 16;
  return v.f;
}

// ---------------------------------------------------------------------------
// Kernel 0: q fp32 -> Qb bf16 [b][l][d]  and  Qt bf16 [b][d][l]
// ---------------------------------------------------------------------------
__global__ __launch_bounds__(256) void convert_kernel(
    const float* __restrict__ q, uint16_t* __restrict__ qb,
    uint16_t* __restrict__ qt) {
  __shared__ uint16_t tile[64][72];
  int b = blockIdx.z;
  int l0 = blockIdx.x * 64, d0 = blockIdx.y * 64;
  int t = threadIdx.x;
  int r = t >> 4;
  int c4 = (t & 15) * 4;
  const float* qsrc = q + (size_t)b * NL * ND;
  uint16_t* qbb = qb + (size_t)b * NL * ND;
  uint16_t* qtb = qt + (size_t)b * ND * NL;
#pragma unroll
  for (int i = 0; i < 4; i++) {
    int row = r + 16 * i;
    float4 v = *(const float4*)(qsrc + (size_t)(l0 + row) * ND + d0 + c4);
    ushort4 h;
    h.x = f2bf(v.x); h.y = f2bf(v.y); h.z = f2bf(v.z); h.w = f2bf(v.w);
    *(ushort4*)(qbb + (size_t)(l0 + row) * ND + d0 + c4) = h;
    tile[row][c4 + 0] = h.x; tile[row][c4 + 1] = h.y;
    tile[row][c4 + 2] = h.z; tile[row][c4 + 3] = h.w;
  }
  __syncthreads();
#pragma unroll
  for (int i = 0; i < 4; i++) {
    int drow = r + 16 * i;
    ushort4 h;
    h.x = tile[c4 + 0][drow]; h.y = tile[c4 + 1][drow];
    h.z = tile[c4 + 2][drow]; h.w = tile[c4 + 3][drow];
    *(ushort4*)(qtb + (size_t)(d0 + drow) * NL + l0 + c4) = h;
  }
}

// ---------------------------------------------------------------------------
// Fused attention kernel, barrier-free main loops.
// One block owns 64 m-rows end-to-end. 512 threads = 8 waves:
//   wave = (wmw: 4-way m-split, 16 rows) x (wnh: 2-way n-half QK / d-half PV)
//
// QK: S = Qb Qb^T; B-fragments loaded DIRECTLY global->reg (bf16x8, each wave
//     instr reads 16 full 64B lines), 2-deep register prefetch, NO barriers.
//     P = exp(S/16) (S==0 -> 0) written bf16 into LDS P[64][1024] with
//     granule-XOR swizzle; rowsums accumulated in registers.
// ONE __syncthreads(): P + rowsums become block-visible.
// PV: out = (P @ Q) * inv_rowsum; V-fragments DIRECTLY global->reg from qt,
//     2-deep register prefetch, NO barriers. P expansion to normalized f32
//     attn overlaps the MFMAs (one 32-n chunk per iteration).
// LDS: P 128 KB + rowsums 0.5 KB -> 1 block/CU, 2 waves/SIMD; latency hiding
// comes from compiler-scheduled vmcnt ILP (large VGPR headroom), not barriers.
// ---------------------------------------------------------------------------
__global__ __launch_bounds__(512) void attn_kernel(
    const uint16_t* __restrict__ qb, const uint16_t* __restrict__ qt,
    float* __restrict__ attn, float* __restrict__ out) {
  __shared__ alignas(16) uint16_t P[64 * 1024];  // 128 KB, swizzled granules
  __shared__ float rsums[64][2];
  int b = blockIdx.z;
  int m0 = blockIdx.x * 64;
  const uint16_t* Q = qb + (size_t)b * NL * ND;
  const uint16_t* Bt = qt + (size_t)b * ND * NL;
  int tid = threadIdx.x, lane = tid & 63, wave = tid >> 6;
  int wmw = wave >> 1;   // 0..3 : m-rows [wmw*16, wmw*16+16)
  int wnh = wave & 1;    // 0..1 : n-half (QK) / d-half (PV)
  int quad = lane >> 4, l15 = lane & 15;
  int mw = wmw * 16 + l15;  // this lane's A-frag m-row (local 0..63)

  // ---- A-fragments, direct global -> registers (one-time, 32 KB/block) ----
  bf16x8 af[8];
#pragma unroll
  for (int kk = 0; kk < 8; kk++)
    af[kk] = *(const bf16x8*)(Q + (size_t)(m0 + mw) * ND + kk * 32 + quad * 8);

  // ---- QK phase: direct-load B fragments, 2-deep prefetch, no barriers ----
  float rsum[4] = {0.f, 0.f, 0.f, 0.f};
  const float kf = 0.09016844005555f;  // log2(e)/16
  int nrow = wnh * 64 + l15;           // + t*16 below
  for (int ns = 0; ns < 8; ns++) {
    int n0 = ns * 128;
    f32x4 sacc[4] = {};
    bf16x8 bq[2][4];
#pragma unroll
    for (int t = 0; t < 4; t++)
      bq[0][t] = *(const bf16x8*)(Q + (size_t)(n0 + nrow + t * 16) * ND +
                                  quad * 8);
#pragma unroll
    for (int kk = 0; kk < 8; kk++) {
      if (kk < 7) {
#pragma unroll
        for (int t = 0; t < 4; t++)
          bq[(kk + 1) & 1][t] =
              *(const bf16x8*)(Q + (size_t)(n0 + nrow + t * 16) * ND +
                               (kk + 1) * 32 + quad * 8);
      }
#pragma unroll
      for (int t = 0; t < 4; t++)
        sacc[t] = __builtin_amdgcn_mfma_f32_16x16x32_bf16(
            af[kk], bq[kk & 1][t], sacc[t], 0, 0, 0);
    }
    // epilogue for this n-step: exp -> P (LDS, swizzled) + rowsum partials
#pragma unroll
    for (int t = 0; t < 4; t++) {
      int n = n0 + wnh * 64 + t * 16 + l15;
      int g = n >> 3, e = n & 7;
#pragma unroll
      for (int j = 0; j < 4; j++) {
        int m = wmw * 16 + quad * 4 + j;
        float s = sacc[t][j];
        float ev = (s == 0.0f) ? 0.0f : __builtin_amdgcn_exp2f(s * kf);
        P[m * 1024 + (((g ^ (m & 7)) << 3) + e)] = f2bf(ev);
        rsum[j] += ev;
      }
    }
  }

  // ---- rowsum reduce -> LDS; single phase barrier -------------------------
#pragma unroll
  for (int j = 0; j < 4; j++) {
    float v = rsum[j];
    v += __shfl_xor(v, 1, 64);
    v += __shfl_xor(v, 2, 64);
    v += __shfl_xor(v, 4, 64);
    v += __shfl_xor(v, 8, 64);
    if (l15 == 0) rsums[wmw * 16 + quad * 4 + j][wnh] = v;
  }
  __syncthreads();  // P + rowsums visible to all waves
  float invo[4];
#pragma unroll
  for (int j = 0; j < 4; j++) {
    int r = wmw * 16 + quad * 4 + j;
    float s = rsums[r][0] + rsums[r][1];
    invo[j] = (s > 0.f) ? 1.f / s : 0.f;
  }
  int xm = tid >> 3, xs = tid & 7;  // expand assignment: row, 4-f32 slice
  float sx = rsums[xm][0] + rsums[xm][1];
  float invx = (sx > 0.f) ? 1.f / sx : 0.f;

  // ---- PV phase: direct-load V fragments, 2-deep prefetch, no barriers ----
  f32x4 pacc[8] = {};
  bf16x8 vb[2][8], pa[2];
  int drow = wnh * 128 + l15;  // + t*16 below
#pragma unroll
  for (int t = 0; t < 8; t++)
    vb[0][t] = *(const bf16x8*)(Bt + (size_t)(drow + t * 16) * NL + quad * 8);
  pa[0] = *(const bf16x8*)(P + mw * 1024 + ((quad ^ (mw & 7)) << 3));
  float* attnb = attn + ((size_t)b * NL + m0) * NL;
#pragma unroll 2
  for (int c = 0; c < 32; c++) {
    int cur = c & 1;
    if (c < 31) {
#pragma unroll
      for (int t = 0; t < 8; t++)
        vb[cur ^ 1][t] = *(const bf16x8*)(Bt + (size_t)(drow + t * 16) * NL +
                                          (c + 1) * 32 + quad * 8);
      int gP = (c + 1) * 4 + quad;
      pa[cur ^ 1] = *(const bf16x8*)(P + mw * 1024 + ((gP ^ (mw & 7)) << 3));
    }
    // expansion of chunk c (independent of vb/pa; overlaps load latency)
    {
      int gx = c * 4 + (xs >> 1);
      u16x4 h = *(const u16x4*)(P + xm * 1024 +
                                (((gx ^ (xm & 7)) << 3) + (xs & 1) * 4));
      float4 v4;
      v4.x = bf2f(h[0]) * invx; v4.y = bf2f(h[1]) * invx;
      v4.z = bf2f(h[2]) * invx; v4.w = bf2f(h[3]) * invx;
      *(float4*)(attnb + (size_t)xm * NL + c * 32 + xs * 4) = v4;
    }
#pragma unroll
    for (int t = 0; t < 8; t++)
      pacc[t] = __builtin_amdgcn_mfma_f32_16x16x32_bf16(pa[cur], vb[cur][t],
                                                        pacc[t], 0, 0, 0);
  }

  // ---- out epilogue -------------------------------------------------------
  float* O = out + (size_t)b * NL * ND + (size_t)m0 * ND;
#pragma unroll
  for (int t = 0; t < 8; t++) {
    int col = wnh * 128 + t * 16 + l15;
#pragma unroll
    for (int j = 0; j < 4; j++) {
      int r = wmw * 16 + quad * 4 + j;
      O[(size_t)r * ND + col] = pacc[t][j] * invo[j];
    }
  }
}

// ---------------------------------------------------------------------------
extern "C" void kernel_launch(void* const* d_in, const int* in_sizes, int n_in,
                              void* d_out, int out_size, void* d_ws,
                              size_t ws_size, hipStream_t stream) {
  (void)in_sizes; (void)n_in; (void)out_size; (void)ws_size;
  const float* q = (const float*)d_in[0];
  float* out = (float*)d_out;
  float* attn = out + (size_t)NB * NL * ND;  // [output | attn] concat
  uint16_t* qb = (uint16_t*)d_ws;            // 16 MiB
  uint16_t* qt = qb + (size_t)NB * NL * ND;  // 16 MiB

  convert_kernel<<<dim3(16, 4, NB), 256, 0, stream>>>(q, qb, qt);
  attn_kernel<<<dim3(16, 1, NB), 512, 0, stream>>>(qb, qt, attn, out);
}

// Round 6
// 266.152 us; speedup vs baseline: 1.5113x; 1.5113x over previous
//
#include <hip/hip_runtime.h>
#include <stdint.h>

#define NB 32
#define NL 1024
#define ND 256

typedef __attribute__((ext_vector_type(8))) __bf16 bf16x8;
typedef __attribute__((ext_vector_type(4))) float f32x4;

__device__ __forceinline__ uint16_t f2bf(float f) {
  union { float f; uint32_t u; } v; v.f = f;
  return (uint16_t)((v.u + 0x7fffu + ((v.u >> 16) & 1u)) >> 16);
}
__device__ __forceinline__ float bf2f(uint16_t h) {
  union { uint32_t u; float f; } v; v.u = ((uint32_t)h) << 16;
  return v.f;
}

#define GLD_LDS16(g, l)                                                        \
  __builtin_amdgcn_global_load_lds(                                            \
      (__attribute__((address_space(1))) void*)(g),                            \
      (__attribute__((address_space(3))) void*)(l), 16, 0, 0)

// ---------------------------------------------------------------------------
// Kernel 0: q fp32 -> Qb bf16 [b][l][d]  and  Qt bf16 [b][d][l]
// (measured at its memory roofline — unchanged)
// ---------------------------------------------------------------------------
__global__ __launch_bounds__(256) void convert_kernel(
    const float* __restrict__ q, uint16_t* __restrict__ qb,
    uint16_t* __restrict__ qt) {
  __shared__ uint16_t tile[64][72];
  int b = blockIdx.z;
  int l0 = blockIdx.x * 64, d0 = blockIdx.y * 64;
  int t = threadIdx.x;
  int r = t >> 4;
  int c4 = (t & 15) * 4;
  const float* qsrc = q + (size_t)b * NL * ND;
  uint16_t* qbb = qb + (size_t)b * NL * ND;
  uint16_t* qtb = qt + (size_t)b * ND * NL;
#pragma unroll
  for (int i = 0; i < 4; i++) {
    int row = r + 16 * i;
    float4 v = *(const float4*)(qsrc + (size_t)(l0 + row) * ND + d0 + c4);
    ushort4 h;
    h.x = f2bf(v.x); h.y = f2bf(v.y); h.z = f2bf(v.z); h.w = f2bf(v.w);
    *(ushort4*)(qbb + (size_t)(l0 + row) * ND + d0 + c4) = h;
    tile[row][c4 + 0] = h.x; tile[row][c4 + 1] = h.y;
    tile[row][c4 + 2] = h.z; tile[row][c4 + 3] = h.w;
  }
  __syncthreads();
#pragma unroll
  for (int i = 0; i < 4; i++) {
    int drow = r + 16 * i;
    ushort4 h;
    h.x = tile[c4 + 0][drow]; h.y = tile[c4 + 1][drow];
    h.z = tile[c4 + 2][drow]; h.w = tile[c4 + 3][drow];
    *(ushort4*)(qtb + (size_t)(d0 + drow) * NL + l0 + c4) = h;
  }
}

// ---------------------------------------------------------------------------
// Fused attention kernel, depth-3 counted-vmcnt pipelined (T3+T4).
// One block owns 64 m-rows. 512 threads = 8 waves:
//   wave = (wmw: 4-way m-split, 16 rows) x (wnh: 2-way n-half QK / d-half PV)
// LDS: P[64][1024] bf16 (128 KB, XOR-granule swizzle) + 3 x 8 KB staging pool
//      + rowsums (156.5 KB total).
// Both phases run 64 granule-steps; granule = 8 KB staged by one
// global_load_lds per thread. Per step: counted s_waitcnt vmcnt(N) (never 0)
// + raw s_barrier; ds_read fragments; lgkmcnt(0) + s_barrier; restage 3 ahead;
// MFMA. Stage loads fly ~3 steps (>600 cyc) before use -> latency covered;
// no __syncthreads() in the loops so the compiler never drains vmcnt to 0.
// vmcnt audit (per thread, in-order completion):
//   QK stream: af0..af7, s0..s2, then 1 stage/step -> stage s at pos 8+s,
//   issued 11+s at wait of step s -> vmcnt(2) exact, all steps.
//   PV stream: s0,s1,s2,[st3,w0],[st4,w1],... -> stage s at pos 2s-3 (s>=3),
//   issued 3+2s at wait -> 5 outstanding after stage-s completes: ramp
//   2/3/4 then steady vmcnt(5) exact.
// PV granule = (chunk c, d-half dh): waves with wnh==dh consume; the f32 attn
// expansion (one float2/thread/granule, normalized) overlaps as fire-and-
// forget stores counted in the vmcnt ramp.
// Grid: flat 512 blocks with bijective XCD swizzle -> each XCD owns 4 whole
// batches -> Qb/qt panels HBM-fetched once per batch.
// ---------------------------------------------------------------------------
__global__ __launch_bounds__(512) void attn_kernel(
    const uint16_t* __restrict__ qb, const uint16_t* __restrict__ qt,
    float* __restrict__ attn, float* __restrict__ out) {
  __shared__ alignas(16) uint16_t P[64 * 1024];   // 128 KB
  __shared__ alignas(16) uint16_t pool[3][4096];  // 3 x 8 KB
  __shared__ float rsums[64][2];

  // bijective XCD swizzle: 512 wgs / 8 xcds = 64 per xcd, contiguous chunk
  int bid = blockIdx.x;
  int wg = (bid & 7) * 64 + (bid >> 3);
  int b = wg >> 4;            // batch
  int m0 = (wg & 15) * 64;    // m-tile

  const uint16_t* Q = qb + (size_t)b * NL * ND;
  const uint16_t* Bt = qt + (size_t)b * ND * NL;
  int tid = threadIdx.x, lane = tid & 63, wave = tid >> 6;
  int wmw = wave >> 1;   // m-split
  int wnh = wave & 1;    // n-half (QK) / d-half (PV)
  int quad = lane >> 4, l15 = lane & 15;
  int mw = wmw * 16 + l15;

  // ---- A-fragments, direct global -> registers (one-time) -----------------
  bf16x8 af[8];
#pragma unroll
  for (int kk = 0; kk < 8; kk++)
    af[kk] = *(const bf16x8*)(Q + (size_t)(m0 + mw) * ND + kk * 32 + quad * 8);

  // ---- QK phase: 64 granule-steps, depth-3 counted pipeline ---------------
  // granule s: ns = s>>3 (n-step of 128 rows), kk = s&7 (k-chunk of 32)
  auto stageQK = [&](int s, int bufi) {
    int ns = s >> 3, kk = s & 7;
    int row = tid >> 2, cc = tid & 3;
    int sw = (row >> 1) & 3;
    GLD_LDS16(Q + (size_t)(ns * 128 + row) * ND + kk * 32 + ((cc ^ sw) * 8),
              pool[bufi] + (size_t)(wave * 64) * 8);
  };
  stageQK(0, 0); stageQK(1, 1); stageQK(2, 2);

  float rsum[4] = {0.f, 0.f, 0.f, 0.f};
  const float kf = 0.09016844005555f;  // log2(e)/16
  int buf = 0;
  for (int ns = 0; ns < 8; ns++) {
    f32x4 sacc[4] = {};
#pragma unroll
    for (int kk = 0; kk < 8; kk++) {
      asm volatile("s_waitcnt vmcnt(2)" ::: "memory");
      __builtin_amdgcn_s_barrier();  // buf's granule fully staged
      const uint16_t* Bb = pool[buf];
      bf16x8 bq[4];
#pragma unroll
      for (int t = 0; t < 4; t++) {
        int rb = wnh * 64 + t * 16 + l15;
        bq[t] = *(const bf16x8*)(Bb + rb * 32 + ((quad ^ ((rb >> 1) & 3)) * 8));
      }
      asm volatile("s_waitcnt lgkmcnt(0)" ::: "memory");
      __builtin_amdgcn_s_barrier();  // all waves done reading buf
      int s3 = ns * 8 + kk + 3;
      if (s3 < 64) stageQK(s3, buf);
#pragma unroll
      for (int t = 0; t < 4; t++)
        sacc[t] = __builtin_amdgcn_mfma_f32_16x16x32_bf16(af[kk], bq[t],
                                                          sacc[t], 0, 0, 0);
      buf = (buf == 2) ? 0 : buf + 1;
    }
    // epilogue for this n-step: exp -> P (LDS, swizzled) + rowsum partials
#pragma unroll
    for (int t = 0; t < 4; t++) {
      int n = ns * 128 + wnh * 64 + t * 16 + l15;
      int g = n >> 3, e = n & 7;
#pragma unroll
      for (int j = 0; j < 4; j++) {
        int m = wmw * 16 + quad * 4 + j;
        float s = sacc[t][j];
        float ev = (s == 0.0f) ? 0.0f : __builtin_amdgcn_exp2f(s * kf);
        P[m * 1024 + (((g ^ (m & 7)) << 3) + e)] = f2bf(ev);
        rsum[j] += ev;
      }
    }
  }

  // ---- rowsum reduce -> LDS; single full-drain phase barrier --------------
#pragma unroll
  for (int j = 0; j < 4; j++) {
    float v = rsum[j];
    v += __shfl_xor(v, 1, 64);
    v += __shfl_xor(v, 2, 64);
    v += __shfl_xor(v, 4, 64);
    v += __shfl_xor(v, 8, 64);
    if (l15 == 0) rsums[wmw * 16 + quad * 4 + j][wnh] = v;
  }
  __syncthreads();  // P + rsums visible; all QK staging/reads drained
  float invo[4];
#pragma unroll
  for (int j = 0; j < 4; j++) {
    int r = wmw * 16 + quad * 4 + j;
    float s = rsums[r][0] + rsums[r][1];
    invo[j] = (s > 0.f) ? 1.f / s : 0.f;
  }
  int xm = tid >> 3, xs = tid & 7;  // expansion: row, 8-col slice pair
  float sx = rsums[xm][0] + rsums[xm][1];
  float invx = (sx > 0.f) ? 1.f / sx : 0.f;
  float* attnb = attn + ((size_t)b * NL + m0) * NL;

  // ---- PV phase: 64 granule-steps (chunk c, d-half dh), depth-3 -----------
  auto stagePV = [&](int g, int bufi) {
    int c = g >> 1, dh = g & 1;
    int row = tid >> 2, cc = tid & 3;
    int sw = (row >> 1) & 3;
    GLD_LDS16(Bt + (size_t)(dh * 128 + row) * NL + c * 32 + ((cc ^ sw) * 8),
              pool[bufi] + (size_t)(wave * 64) * 8);
  };
  f32x4 pacc[8] = {};
  int pvbuf = 0;
  stagePV(0, 0); stagePV(1, 1); stagePV(2, 2);

#define PV_STEP(c, dh, VMC)                                                    \
  {                                                                            \
    asm volatile("s_waitcnt vmcnt(" #VMC ")" ::: "memory");                    \
    __builtin_amdgcn_s_barrier();                                              \
    bf16x8 vb[8], pa;                                                          \
    bool act = (wnh == (dh));                                                  \
    if (act) {                                                                 \
      const uint16_t* Vb = pool[pvbuf];                                        \
      _Pragma("unroll")                                                        \
      for (int t = 0; t < 8; t++) {                                            \
        int rb = t * 16 + l15;                                                 \
        vb[t] = *(const bf16x8*)(Vb + rb * 32 +                                \
                                 ((quad ^ ((rb >> 1) & 3)) * 8));              \
      }                                                                        \
      int gP = (c) * 4 + quad;                                                 \
      pa = *(const bf16x8*)(P + mw * 1024 + ((gP ^ (mw & 7)) << 3));           \
    }                                                                          \
    int nx = (c) * 32 + (dh) * 16 + xs * 2;                                    \
    int gx = nx >> 3;                                                          \
    uint32_t pw = *(const uint32_t*)(P + xm * 1024 +                           \
                                     ((gx ^ (xm & 7)) << 3) + (nx & 7));       \
    asm volatile("s_waitcnt lgkmcnt(0)" ::: "memory");                         \
    __builtin_amdgcn_s_barrier();                                              \
    int g3 = (c) * 2 + (dh) + 3;                                               \
    if (g3 < 64) stagePV(g3, pvbuf);                                           \
    {                                                                          \
      float2 v2;                                                               \
      v2.x = bf2f((uint16_t)(pw & 0xffffu)) * invx;                            \
      v2.y = bf2f((uint16_t)(pw >> 16)) * invx;                                \
      *(float2*)(attnb + (size_t)xm * NL + nx) = v2;                           \
    }                                                                          \
    if (act) {                                                                 \
      _Pragma("unroll")                                                        \
      for (int t = 0; t < 8; t++)                                              \
        pacc[t] = __builtin_amdgcn_mfma_f32_16x16x32_bf16(pa, vb[t],           \
                                                          pacc[t], 0, 0, 0);   \
    }                                                                          \
    pvbuf = (pvbuf == 2) ? 0 : pvbuf + 1;                                      \
  }

  // vmcnt ramp: stores enter the vm stream one per granule
  PV_STEP(0, 0, 2)
  PV_STEP(0, 1, 3)
  PV_STEP(1, 0, 4)
  PV_STEP(1, 1, 5)
  for (int c = 2; c < 32; c++) {
    PV_STEP(c, 0, 5)
    PV_STEP(c, 1, 5)
  }
#undef PV_STEP

  // ---- out epilogue -------------------------------------------------------
  float* O = out + (size_t)b * NL * ND + (size_t)m0 * ND;
#pragma unroll
  for (int t = 0; t < 8; t++) {
    int col = wnh * 128 + t * 16 + l15;
#pragma unroll
    for (int j = 0; j < 4; j++) {
      int r = wmw * 16 + quad * 4 + j;
      O[(size_t)r * ND + col] = pacc[t][j] * invo[j];
    }
  }
}

// ---------------------------------------------------------------------------
extern "C" void kernel_launch(void* const* d_in, const int* in_sizes, int n_in,
                              void* d_out, int out_size, void* d_ws,
                              size_t ws_size, hipStream_t stream) {
  (void)in_sizes; (void)n_in; (void)out_size; (void)ws_size;
  const float* q = (const float*)d_in[0];
  float* out = (float*)d_out;
  float* attn = out + (size_t)NB * NL * ND;  // [output | attn] concat
  uint16_t* qb = (uint16_t*)d_ws;            // 16 MiB
  uint16_t* qt = qb + (size_t)NB * NL * ND;  // 16 MiB

  convert_kernel<<<dim3(16, 4, NB), 256, 0, stream>>>(q, qb, qt);
  attn_kernel<<<dim3(512, 1, 1), 512, 0, stream>>>(qb, qt, attn, out);
}

// Round 7
// 242.404 us; speedup vs baseline: 1.6593x; 1.0980x over previous
//
#include <hip/hip_runtime.h>
#include <stdint.h>

#define NB 32
#define NL 1024
#define ND 256
// attn fp32 row = 1024 f32 = 4096 B = 2048 u16 slots. Pack bf16 P in slots
// [0,1024); per-row partial sums (8 n-blocks) live in f32 slots [512,520).
#define ROWU16 2048

typedef __attribute__((ext_vector_type(8))) __bf16 bf16x8;
typedef __attribute__((ext_vector_type(8))) uint16_t u16x8;
typedef __attribute__((ext_vector_type(4))) float f32x4;

__device__ __forceinline__ uint16_t f2bf(float f) {
  union { float f; uint32_t u; } v; v.f = f;
  return (uint16_t)((v.u + 0x7fffu + ((v.u >> 16) & 1u)) >> 16);
}
__device__ __forceinline__ float bf2f(uint16_t h) {
  union { uint32_t u; float f; } v; v.u = ((uint32_t)h) << 16;
  return v.f;
}

#define GLD_LDS16(g, l)                                                        \
  __builtin_amdgcn_global_load_lds(                                            \
      (__attribute__((address_space(1))) void*)(g),                            \
      (__attribute__((address_space(3))) void*)(l), 16, 0, 0)

// ---------------------------------------------------------------------------
// Kernel 0: q fp32 -> Qb bf16 [b][l][d]  and  Qt bf16 [b][d][l]
// (memory-roofline bound — unchanged, measured ~27 us)
// ---------------------------------------------------------------------------
__global__ __launch_bounds__(256) void convert_kernel(
    const float* __restrict__ q, uint16_t* __restrict__ qb,
    uint16_t* __restrict__ qt) {
  __shared__ uint16_t tile[64][72];
  int b = blockIdx.z;
  int l0 = blockIdx.x * 64, d0 = blockIdx.y * 64;
  int t = threadIdx.x;
  int r = t >> 4;
  int c4 = (t & 15) * 4;
  const float* qsrc = q + (size_t)b * NL * ND;
  uint16_t* qbb = qb + (size_t)b * NL * ND;
  uint16_t* qtb = qt + (size_t)b * ND * NL;
#pragma unroll
  for (int i = 0; i < 4; i++) {
    int row = r + 16 * i;
    float4 v = *(const float4*)(qsrc + (size_t)(l0 + row) * ND + d0 + c4);
    ushort4 h;
    h.x = f2bf(v.x); h.y = f2bf(v.y); h.z = f2bf(v.z); h.w = f2bf(v.w);
    *(ushort4*)(qbb + (size_t)(l0 + row) * ND + d0 + c4) = h;
    tile[row][c4 + 0] = h.x; tile[row][c4 + 1] = h.y;
    tile[row][c4 + 2] = h.z; tile[row][c4 + 3] = h.w;
  }
  __syncthreads();
#pragma unroll
  for (int i = 0; i < 4; i++) {
    int drow = r + 16 * i;
    ushort4 h;
    h.x = tile[c4 + 0][drow]; h.y = tile[c4 + 1][drow];
    h.z = tile[c4 + 2][drow]; h.w = tile[c4 + 3][drow];
    *(ushort4*)(qtb + (size_t)(d0 + drow) * NL + l0 + c4) = h;
  }
}

// ---------------------------------------------------------------------------
// Kernel 1: e = exp(S/16) (s==0 -> 0), S = Qb Qb^T. Writes bf16 e packed into
// attn rows + per-(row, n-block) fp32 partial sums into spare slots.
// 128x128 tile, 256 threads, flat grid 2048 with bijective XCD swizzle:
// each XCD owns 4 whole batches -> Q panels L2-resident per XCD.
// ~5 blocks/CU resident -> inter-block overlap hides the barrier drains.
// ---------------------------------------------------------------------------
__global__ __launch_bounds__(256) void qk_kernel(
    const uint16_t* __restrict__ qb, float* __restrict__ attn_f32) {
  __shared__ alignas(16) uint16_t As[128 * 32];
  __shared__ alignas(16) uint16_t Bs[128 * 32];
  __shared__ float rp[128][2];
  // XCD swizzle: 2048 wgs, 256 contiguous per XCD = batches [4x, 4x+4)
  int wg = (blockIdx.x & 7) * 256 + (blockIdx.x >> 3);
  int b = wg >> 6;
  int m0 = ((wg >> 3) & 7) * 128, n0 = (wg & 7) * 128;
  int nxi = wg & 7;  // n-block index (rowsum slot)
  const uint16_t* Q = qb + (size_t)b * NL * ND;
  int tid = threadIdx.x, lane = tid & 63, wave = tid >> 6;
  int wm = (wave & 1) * 64, wn = (wave >> 1) * 64;
  int quad = lane >> 4, l15 = lane & 15;
  f32x4 acc[4][4] = {};

  for (int k0 = 0; k0 < ND; k0 += 32) {
    __syncthreads();
#pragma unroll
    for (int i = 0; i < 2; i++) {
      int c = i * 256 + wave * 64 + lane;
      int row = c >> 2, cc = c & 3;
      int sw = (row >> 1) & 3;
      int gc = k0 + ((cc ^ sw) * 8);
      GLD_LDS16(Q + (size_t)(m0 + row) * ND + gc,
                As + (size_t)(i * 256 + wave * 64) * 8);
      GLD_LDS16(Q + (size_t)(n0 + row) * ND + gc,
                Bs + (size_t)(i * 256 + wave * 64) * 8);
    }
    __syncthreads();
    bf16x8 af[4], bfr[4];
#pragma unroll
    for (int t = 0; t < 4; t++) {
      int ra = wm + t * 16 + l15;
      af[t] = *(const bf16x8*)(As + ra * 32 + ((quad ^ ((ra >> 1) & 3)) * 8));
      int rb = wn + t * 16 + l15;
      bfr[t] = *(const bf16x8*)(Bs + rb * 32 + ((quad ^ ((rb >> 1) & 3)) * 8));
    }
#pragma unroll
    for (int tm = 0; tm < 4; tm++)
#pragma unroll
      for (int tn = 0; tn < 4; tn++)
        acc[tm][tn] = __builtin_amdgcn_mfma_f32_16x16x32_bf16(
            af[tm], bfr[tn], acc[tm][tn], 0, 0, 0);
  }

  const float kf = 0.09016844005555f;  // log2(e)/16
  uint16_t* attn_u16 = (uint16_t*)attn_f32;
  size_t gbase = (size_t)b * NL;
#pragma unroll
  for (int tm = 0; tm < 4; tm++) {
    int rbl = wm + tm * 16 + quad * 4;  // local row base (j adds 0..3)
    float rsum[4] = {0.f, 0.f, 0.f, 0.f};
#pragma unroll
    for (int tn = 0; tn < 4; tn++) {
      int col = n0 + wn + tn * 16 + l15;
#pragma unroll
      for (int j = 0; j < 4; j++) {
        float s = acc[tm][tn][j];
        float e = (s == 0.0f) ? 0.0f : __builtin_amdgcn_exp2f(s * kf);
        union { __bf16 b; uint16_t u; } cv;
        cv.b = (__bf16)e;  // native cvt, RNE
        attn_u16[(gbase + m0 + rbl + j) * ROWU16 + col] = cv.u;
        rsum[j] += e;
      }
    }
#pragma unroll
    for (int j = 0; j < 4; j++) {
      float v = rsum[j];
      v += __shfl_xor(v, 1, 64);
      v += __shfl_xor(v, 2, 64);
      v += __shfl_xor(v, 4, 64);
      v += __shfl_xor(v, 8, 64);
      if (l15 == 0) rp[rbl + j][wave >> 1] = v;
    }
  }
  __syncthreads();
  if (tid < 128) {
    float s = rp[tid][0] + rp[tid][1];
    attn_f32[(gbase + m0 + tid) * (size_t)NL + 512 + nxi] = s;
  }
}

// ---------------------------------------------------------------------------
// Kernel 2 (fused): out = (P @ Q) * inv_rowsum AND in-place expansion of the
// packed bf16 P rows into normalized fp32 attn rows.
// Tile 64 (m) x 256 (full D), 256 threads (4 waves). Flat grid 512 with the
// SAME XCD mapping as qk (batch b -> XCD b/4), so packed-P reads hit the L2
// that qk just wrote. Each block exclusively owns its 64 attn rows.
// K runs HIGH -> LOW; expansion of chunk k0 is computed in iteration k0 but
// stored one iteration later beside the gld_lds issue (store drain overlaps
// load drain). Deferred store range [4*k0+128, 4*k0+256) never intersects
// remaining packed reads [2*k0, 2*k0+64).
// ---------------------------------------------------------------------------
__global__ __launch_bounds__(256) void pv_kernel(
    float* __restrict__ attn_f32, const uint16_t* __restrict__ qt,
    float* __restrict__ out) {
  __shared__ alignas(16) uint16_t As[64 * 32];
  __shared__ alignas(16) uint16_t Bs[256 * 32];
  __shared__ float inv_lds[64];
  // XCD swizzle: 512 wgs, 64 contiguous per XCD = batches [4x, 4x+4)
  int wg = (blockIdx.x & 7) * 64 + (blockIdx.x >> 3);
  int b = wg >> 4;
  int m0 = (wg & 15) * 64;
  const uint16_t* Ap = (const uint16_t*)attn_f32 + (size_t)b * NL * ROWU16;
  const uint16_t* Bt = qt + (size_t)b * ND * NL;
  int tid = threadIdx.x, lane = tid & 63, wave = tid >> 6;
  int wn = wave * 64;  // wave covers cols [wn, wn+64) of D=256
  int quad = lane >> 4, l15 = lane & 15;
  f32x4 acc[4][4] = {};

  if (tid < 64) {
    const float* pf = attn_f32 + (size_t)(b * NL + m0 + tid) * NL + 512;
    float s = pf[0] + pf[1] + pf[2] + pf[3] + pf[4] + pf[5] + pf[6] + pf[7];
    inv_lds[tid] = (s > 0.0f) ? 1.0f / s : 0.0f;
  }

  // expansion assignment: 256 threads cover 64 rows x 4 chunks-of-8-u16
  int xr = tid >> 2;  // local row 0..63
  int xc = tid & 3;   // which 8-u16 chunk within the 32-u16 K-step
  int xsw = (xr >> 1) & 3;
  float* xrow = attn_f32 + (size_t)(b * NL + m0 + xr) * NL;

  float4 p0, p1;
  float* pdst = nullptr;

  for (int k0 = NL - 32; k0 >= 0; k0 -= 32) {
    __syncthreads();
    // flush previous chunk's expansion (drains together with gld_lds below)
    if (k0 != NL - 32) {
      ((float4*)pdst)[0] = p0;
      ((float4*)pdst)[1] = p1;
    }
    {
      // A: 64 rows x 32 u16 = 4 KB, one gld_lds across 256 threads
      int row = tid >> 2, cc = tid & 3;
      int sw = (row >> 1) & 3;
      int gc = k0 + ((cc ^ sw) * 8);
      GLD_LDS16(Ap + (size_t)(m0 + row) * ROWU16 + gc,
                As + (size_t)(wave * 64) * 8);
    }
#pragma unroll
    for (int i = 0; i < 4; i++) {
      // B: 256 rows x 32 u16 = 16 KB, four gld_lds across 256 threads
      int c = i * 256 + tid;
      int row = c >> 2, cc = c & 3;
      int sw = (row >> 1) & 3;
      int gc = k0 + ((cc ^ sw) * 8);
      GLD_LDS16(Bt + (size_t)row * NL + gc,
                Bs + (size_t)(i * 256 + wave * 64) * 8);
    }
    __syncthreads();
    bf16x8 af[4], bfr[4];
#pragma unroll
    for (int t = 0; t < 4; t++) {
      int ra = t * 16 + l15;
      af[t] = *(const bf16x8*)(As + ra * 32 + ((quad ^ ((ra >> 1) & 3)) * 8));
      int rb = wn + t * 16 + l15;
      bfr[t] = *(const bf16x8*)(Bs + rb * 32 + ((quad ^ ((rb >> 1) & 3)) * 8));
    }
#pragma unroll
    for (int tm = 0; tm < 4; tm++)
#pragma unroll
      for (int tn = 0; tn < 4; tn++)
        acc[tm][tn] = __builtin_amdgcn_mfma_f32_16x16x32_bf16(
            af[tm], bfr[tn], acc[tm][tn], 0, 0, 0);

    // compute this chunk's expansion into registers (reads As; valid until
    // the next top-of-loop barrier). Store happens next iteration.
    {
      u16x8 hv = *(const u16x8*)(As + xr * 32 + ((xc ^ xsw) * 8));
      float inv = inv_lds[xr];
      p0.x = bf2f(hv[0]) * inv;
      p0.y = bf2f(hv[1]) * inv;
      p0.z = bf2f(hv[2]) * inv;
      p0.w = bf2f(hv[3]) * inv;
      p1.x = bf2f(hv[4]) * inv;
      p1.y = bf2f(hv[5]) * inv;
      p1.z = bf2f(hv[6]) * inv;
      p1.w = bf2f(hv[7]) * inv;
      pdst = xrow + k0 + xc * 8;
    }
  }
  // final flush (chunk k0 = 0)
  ((float4*)pdst)[0] = p0;
  ((float4*)pdst)[1] = p1;

  float* O = out + (size_t)b * NL * ND;
#pragma unroll
  for (int tm = 0; tm < 4; tm++) {
    int rbl = tm * 16 + quad * 4;
#pragma unroll
    for (int tn = 0; tn < 4; tn++) {
      int col = wn + tn * 16 + l15;
#pragma unroll
      for (int j = 0; j < 4; j++)
        O[(size_t)(m0 + rbl + j) * ND + col] = acc[tm][tn][j] * inv_lds[rbl + j];
    }
  }
}

// ---------------------------------------------------------------------------
extern "C" void kernel_launch(void* const* d_in, const int* in_sizes, int n_in,
                              void* d_out, int out_size, void* d_ws,
                              size_t ws_size, hipStream_t stream) {
  (void)in_sizes; (void)n_in; (void)out_size; (void)ws_size;
  const float* q = (const float*)d_in[0];
  float* out = (float*)d_out;
  float* attn = out + (size_t)NB * NL * ND;  // [output | attn] concat
  uint16_t* qb = (uint16_t*)d_ws;            // 16 MiB
  uint16_t* qt = qb + (size_t)NB * NL * ND;  // 16 MiB

  convert_kernel<<<dim3(16, 4, NB), 256, 0, stream>>>(q, qb, qt);
  qk_kernel<<<dim3(2048, 1, 1), 256, 0, stream>>>(qb, attn);
  pv_kernel<<<dim3(512, 1, 1), 256, 0, stream>>>(attn, qt, out);
}